// Round 1
// baseline (992.884 us; speedup 1.0000x reference)
//
#include <hip/hip_runtime.h>
#include <cstddef>

// Problem constants (fixed-shape problem)
#define DD   128      // feature dim
#define PP   8192     // nodes per level
#define KK   8        // in-edges per node
#define LLV  16       // levels
#define NN   131072   // total nodes
#define NE   65536    // edges per level (PP*KK)
#define NLVL 15       // levels with edges

__device__ __forceinline__ float4 ld4(const float* p) { return *(const float4*)p; }
__device__ __forceinline__ void st4(float* p, float4 v) { *(float4*)p = v; }

// 32-rows-per-(rg4 group) x 128-col GEMM from LDS: acc[4][4] = tbuf[rg4..rg4+3][:] @ wbuf
// k is processed in chunks of 4 so the tbuf (A) operand is read as float4 via
// ds_read_b128 (broadcast within each 32-lane c4 group) instead of 4x ds_read_b32.
// LDS instrs per k-iter: 2 (was 5) -> moves the loop from LDS-pipe-bound to VALU-bound.
__device__ __forceinline__ void tile_gemm(const float* __restrict__ tbuf,
                                          const float* __restrict__ wbuf,
                                          int rg4, int c4, float acc[4][4]) {
#pragma unroll
  for (int i = 0; i < 4; i++)
#pragma unroll
    for (int j = 0; j < 4; j++) acc[i][j] = 0.f;
  const float4* wb4 = (const float4*)wbuf;
  const float4* tb4 = (const float4*)tbuf;
#pragma unroll 4
  for (int kk = 0; kk < 32; kk++) {
    float4 xv[4];
    float4 wv[4];
#pragma unroll
    for (int i = 0; i < 4; i++) xv[i] = tb4[(rg4 + i) * 32 + kk];
#pragma unroll
    for (int j = 0; j < 4; j++) wv[j] = wb4[(kk * 4 + j) * 32 + c4];
#pragma unroll
    for (int i = 0; i < 4; i++) {
      acc[i][0] = fmaf(xv[i].x, wv[0].x, acc[i][0]);
      acc[i][0] = fmaf(xv[i].y, wv[1].x, acc[i][0]);
      acc[i][0] = fmaf(xv[i].z, wv[2].x, acc[i][0]);
      acc[i][0] = fmaf(xv[i].w, wv[3].x, acc[i][0]);
      acc[i][1] = fmaf(xv[i].x, wv[0].y, acc[i][1]);
      acc[i][1] = fmaf(xv[i].y, wv[1].y, acc[i][1]);
      acc[i][1] = fmaf(xv[i].z, wv[2].y, acc[i][1]);
      acc[i][1] = fmaf(xv[i].w, wv[3].y, acc[i][1]);
      acc[i][2] = fmaf(xv[i].x, wv[0].z, acc[i][2]);
      acc[i][2] = fmaf(xv[i].y, wv[1].z, acc[i][2]);
      acc[i][2] = fmaf(xv[i].z, wv[2].z, acc[i][2]);
      acc[i][2] = fmaf(xv[i].w, wv[3].z, acc[i][2]);
      acc[i][3] = fmaf(xv[i].x, wv[0].w, acc[i][3]);
      acc[i][3] = fmaf(xv[i].y, wv[1].w, acc[i][3]);
      acc[i][3] = fmaf(xv[i].z, wv[2].w, acc[i][3]);
      acc[i][3] = fmaf(xv[i].w, wv[3].w, acc[i][3]);
    }
  }
}

// ---------------- Node transform: h = relu(x@w1+b1)@w2 + b2 ----------------
// 512 threads, 64-row tiles, grid = NN/64 = 2048
__global__ __launch_bounds__(512) void nt_kernel(
    const float* __restrict__ x,
    const float* __restrict__ w1, const float* __restrict__ b1,
    const float* __restrict__ w2, const float* __restrict__ b2,
    float* __restrict__ h) {
  __shared__ float wbuf[128 * 128];   // 64 KB
  __shared__ float tbuf[64 * 128];    // 32 KB
  int tid = threadIdx.x;
  int c4 = tid & 31;
  int rg4 = (tid >> 5) * 4;           // row group base 0..60
  size_t base = (size_t)blockIdx.x * 64;

  float4* wb4 = (float4*)wbuf;
#pragma unroll
  for (int j = 0; j < 8; j++) wb4[tid + j * 512] = ((const float4*)w1)[tid + j * 512];
#pragma unroll
  for (int j = 0; j < 4; j++)
    ((float4*)tbuf)[tid + j * 512] = ((const float4*)(x + base * 128))[tid + j * 512];
  __syncthreads();

  float acc[4][4];
  tile_gemm(tbuf, wbuf, rg4, c4, acc);
  float4 bv = ((const float4*)b1)[c4];
  float4 t[4];
#pragma unroll
  for (int i = 0; i < 4; i++) {
    t[i].x = fmaxf(acc[i][0] + bv.x, 0.f);
    t[i].y = fmaxf(acc[i][1] + bv.y, 0.f);
    t[i].z = fmaxf(acc[i][2] + bv.z, 0.f);
    t[i].w = fmaxf(acc[i][3] + bv.w, 0.f);
  }
  __syncthreads();
#pragma unroll
  for (int i = 0; i < 4; i++) ((float4*)tbuf)[(rg4 + i) * 32 + c4] = t[i];
#pragma unroll
  for (int j = 0; j < 8; j++) wb4[tid + j * 512] = ((const float4*)w2)[tid + j * 512];
  __syncthreads();

  tile_gemm(tbuf, wbuf, rg4, c4, acc);
  float4 b2v = ((const float4*)b2)[c4];
#pragma unroll
  for (int i = 0; i < 4; i++) {
    float4 o;
    o.x = acc[i][0] + b2v.x;
    o.y = acc[i][1] + b2v.y;
    o.z = acc[i][2] + b2v.z;
    o.w = acc[i][3] + b2v.w;
    st4(h + (base + rg4 + i) * 128 + c4 * 4, o);
  }
}

// ---------------- CSR build (reverse-edge transpose) ----------------
__global__ __launch_bounds__(256) void csr_count(const int* __restrict__ src_all,
                                                 int* __restrict__ deg) {
  int e = blockIdx.x * 256 + threadIdx.x;  // grid = 3840 -> exactly 15*65536
  int l = e >> 16;
  int q = src_all[e];
  atomicAdd(&deg[l * PP + q], 1);
}

__global__ __launch_bounds__(256) void csr_scan(const int* __restrict__ deg,
                                                int* __restrict__ offs,
                                                int* __restrict__ cursor) {
  int l = blockIdx.x;
  int t = threadIdx.x;
  const int* d = deg + l * PP;
  __shared__ int ssum[256];
  int loc[32];
  int s = 0;
#pragma unroll
  for (int j = 0; j < 32; j++) { loc[j] = d[t * 32 + j]; s += loc[j]; }
  ssum[t] = s;
  __syncthreads();
  // Hillis-Steele inclusive scan over 256
  for (int off = 1; off < 256; off <<= 1) {
    int v = (t >= off) ? ssum[t - off] : 0;
    __syncthreads();
    ssum[t] += v;
    __syncthreads();
  }
  int run = (t == 0) ? 0 : ssum[t - 1];
#pragma unroll
  for (int j = 0; j < 32; j++) {
    offs[l * (PP + 1) + t * 32 + j] = run;
    cursor[l * PP + t * 32 + j] = run;
    run += loc[j];
  }
  if (t == 255) offs[l * (PP + 1) + PP] = run;
}

__global__ __launch_bounds__(256) void csr_fill(const int* __restrict__ src_all,
                                                int* __restrict__ cursor,
                                                int* __restrict__ edges) {
  int e = blockIdx.x * 256 + threadIdx.x;
  int l = e >> 16;
  int q = src_all[e];
  int pos = atomicAdd(&cursor[l * PP + q], 1);
  edges[l * NE + pos] = (e & (NE - 1)) >> 3;   // dst node p of this fwd edge
}

// ---------------- Fused message-passing step ----------------
// grid = 512: blocks 0..255 = forward level `step`, 256..511 = reverse level 15-step
__global__ __launch_bounds__(256) void mp_step(
    const float* __restrict__ h,
    const int* __restrict__ src_all,
    const int* __restrict__ offs,
    const int* __restrict__ edges,
    const float* __restrict__ fw_upd_w, const float* __restrict__ fw_upd_b,
    const float* __restrict__ fw_pre_w, const float* __restrict__ fw_pre_b,
    const float* __restrict__ bw_upd_w, const float* __restrict__ bw_upd_b,
    const float* __restrict__ bw_pre_w, const float* __restrict__ bw_pre_b,
    const float* __restrict__ mf_in, float* __restrict__ mf_out,
    const float* __restrict__ mb_in, float* __restrict__ mb_out,
    float* __restrict__ out, int step) {
  __shared__ float wbuf[128 * 128];   // 64 KB
  __shared__ float tbuf[32 * 128];    // 16 KB
  int tid = threadIdx.x;
  int c4 = tid & 31;
  int rg4 = (tid >> 5) * 4;           // 0..28
  bool is_fwd = blockIdx.x < 256;
  int tile = (blockIdx.x & 255) * 32;
  int level = is_fwd ? step : 15 - step;
  const float* upd_w = is_fwd ? fw_upd_w : bw_upd_w;
  const float* upd_b = is_fwd ? fw_upd_b : bw_upd_b;
  const float* pre_w = is_fwd ? fw_pre_w : bw_pre_w;
  const float* pre_b = is_fwd ? fw_pre_b : bw_pre_b;
  const float* m_in  = is_fwd ? mf_in : mb_in;
  float* m_out       = is_fwd ? mf_out : mb_out;
  bool has_gather = (step > 0);
  bool has_mout   = (step < 15);
  int col_off = is_fwd ? 0 : 128;

  float4* wb4 = (float4*)wbuf;
#pragma unroll
  for (int j = 0; j < 16; j++) wb4[tid + j * 256] = ((const float4*)upd_w)[tid + j * 256];

  // ---- phase A: gather z into tbuf ----
  if (has_gather) {
    if (is_fwd) {
      const int* src = src_all + (step - 1) * NE;
#pragma unroll
      for (int i = 0; i < 4; i++) {
        int r = rg4 + i;
        int p = tile + r;
        float4 v[8];
#pragma unroll
        for (int k = 0; k < 8; k++) {
          int s = src[p * 8 + k];
          v[k] = ld4(m_in + (size_t)s * 128 + c4 * 4);
        }
        float4 a;
        a.x = ((v[0].x + v[1].x) + (v[2].x + v[3].x)) + ((v[4].x + v[5].x) + (v[6].x + v[7].x));
        a.y = ((v[0].y + v[1].y) + (v[2].y + v[3].y)) + ((v[4].y + v[5].y) + (v[6].y + v[7].y));
        a.z = ((v[0].z + v[1].z) + (v[2].z + v[3].z)) + ((v[4].z + v[5].z) + (v[6].z + v[7].z));
        a.w = ((v[0].w + v[1].w) + (v[2].w + v[3].w)) + ((v[4].w + v[5].w) + (v[6].w + v[7].w));
        a.x *= 0.125f; a.y *= 0.125f; a.z *= 0.125f; a.w *= 0.125f;
        ((float4*)tbuf)[r * 32 + c4] = a;
      }
    } else {
      const int* off_l = offs + level * (PP + 1);
      const int* ep = edges + level * NE;
#pragma unroll
      for (int i = 0; i < 4; i++) {
        int r = rg4 + i;
        int q = tile + r;
        int lo = off_l[q], hi = off_l[q + 1];
        float4 a = {0.f, 0.f, 0.f, 0.f};
        for (int idx = lo; idx < hi; idx++) {
          int p = ep[idx];
          float4 v = ld4(m_in + (size_t)p * 128 + c4 * 4);
          a.x += v.x; a.y += v.y; a.z += v.z; a.w += v.w;
        }
        float inv = (hi > lo) ? 1.0f / (float)(hi - lo) : 0.f;
        a.x *= inv; a.y *= inv; a.z *= inv; a.w *= inv;
        ((float4*)tbuf)[r * 32 + c4] = a;
      }
    }
  } else {
    float4 z = {0.f, 0.f, 0.f, 0.f};
#pragma unroll
    for (int i = 0; i < 4; i++) ((float4*)tbuf)[(rg4 + i) * 32 + c4] = z;
  }
  __syncthreads();

  // ---- phase B: u = relu(z@upd_w + upd_b) + h[level] ; write output half ----
  float acc[4][4];
  tile_gemm(tbuf, wbuf, rg4, c4, acc);
  float4 bv = ((const float4*)upd_b)[c4];
  float4 u[4];
#pragma unroll
  for (int i = 0; i < 4; i++) {
    int n = level * PP + tile + rg4 + i;
    float4 res = ld4(h + (size_t)n * 128 + c4 * 4);
    u[i].x = fmaxf(acc[i][0] + bv.x, 0.f) + res.x;
    u[i].y = fmaxf(acc[i][1] + bv.y, 0.f) + res.y;
    u[i].z = fmaxf(acc[i][2] + bv.z, 0.f) + res.z;
    u[i].w = fmaxf(acc[i][3] + bv.w, 0.f) + res.w;
    st4(out + (size_t)n * 256 + col_off + c4 * 4, u[i]);
  }
  __syncthreads();

  // ---- phase C: m_out = relu(u @ pre_w + pre_b) ----
  if (has_mout) {
#pragma unroll
    for (int i = 0; i < 4; i++) ((float4*)tbuf)[(rg4 + i) * 32 + c4] = u[i];
#pragma unroll
    for (int j = 0; j < 16; j++) wb4[tid + j * 256] = ((const float4*)pre_w)[tid + j * 256];
    __syncthreads();
    tile_gemm(tbuf, wbuf, rg4, c4, acc);
    float4 pv = ((const float4*)pre_b)[c4];
#pragma unroll
    for (int i = 0; i < 4; i++) {
      float4 m;
      m.x = fmaxf(acc[i][0] + pv.x, 0.f);
      m.y = fmaxf(acc[i][1] + pv.y, 0.f);
      m.z = fmaxf(acc[i][2] + pv.z, 0.f);
      m.w = fmaxf(acc[i][3] + pv.w, 0.f);
      st4(m_out + (size_t)(tile + rg4 + i) * 128 + c4 * 4, m);
    }
  }
}

extern "C" void kernel_launch(void* const* d_in, const int* in_sizes, int n_in,
                              void* d_out, int out_size, void* d_ws, size_t ws_size,
                              hipStream_t stream) {
  const float* x      = (const float*)d_in[0];
  const int*   src    = (const int*)d_in[1];
  const float* nt_w1  = (const float*)d_in[2];
  const float* nt_b1  = (const float*)d_in[3];
  const float* nt_w2  = (const float*)d_in[4];
  const float* nt_b2  = (const float*)d_in[5];
  const float* f_pre_w = (const float*)d_in[6];
  const float* f_pre_b = (const float*)d_in[7];
  const float* f_upd_w = (const float*)d_in[8];
  const float* f_upd_b = (const float*)d_in[9];
  const float* b_pre_w = (const float*)d_in[10];
  const float* b_pre_b = (const float*)d_in[11];
  const float* b_upd_w = (const float*)d_in[12];
  const float* b_upd_b = (const float*)d_in[13];
  float* out = (float*)d_out;

  float* wsf = (float*)d_ws;
  float* h   = wsf;                                  // NN*DD
  float* mf0 = h + (size_t)NN * DD;                  // PP*DD each
  float* mf1 = mf0 + (size_t)PP * DD;
  float* mb0 = mf1 + (size_t)PP * DD;
  float* mb1 = mb0 + (size_t)PP * DD;
  int* deg    = (int*)(mb1 + (size_t)PP * DD);       // NLVL*PP
  int* offs   = deg + NLVL * PP;                     // NLVL*(PP+1)
  int* cursor = offs + NLVL * (PP + 1);              // NLVL*PP
  int* edges  = cursor + NLVL * PP;                  // NLVL*NE

  hipMemsetAsync(deg, 0, (size_t)NLVL * PP * sizeof(int), stream);
  nt_kernel<<<NN / 64, 512, 0, stream>>>(x, nt_w1, nt_b1, nt_w2, nt_b2, h);
  csr_count<<<NLVL * NE / 256, 256, 0, stream>>>(src, deg);
  csr_scan<<<NLVL, 256, 0, stream>>>(deg, offs, cursor);
  csr_fill<<<NLVL * NE / 256, 256, 0, stream>>>(src, cursor, edges);

  for (int s = 0; s < 16; s++) {
    const float* mf_in = (s & 1) ? mf0 : mf1;
    float* mf_out      = (s & 1) ? mf1 : mf0;
    const float* mb_in = (s & 1) ? mb0 : mb1;
    float* mb_out      = (s & 1) ? mb1 : mb0;
    mp_step<<<512, 256, 0, stream>>>(h, src, offs, edges,
                                     f_upd_w, f_upd_b, f_pre_w, f_pre_b,
                                     b_upd_w, b_upd_b, b_pre_w, b_pre_b,
                                     mf_in, mf_out, mb_in, mb_out, out, s);
  }
}

// Round 2
// 696.729 us; speedup vs baseline: 1.4251x; 1.4251x over previous
//
#include <hip/hip_runtime.h>
#include <cstddef>
#include <cstdint>

// Problem constants (fixed-shape problem)
#define DD   128      // feature dim
#define PP   8192     // nodes per level
#define KK   8        // in-edges per node
#define LLV  16       // levels
#define NN   131072   // total nodes
#define NE   65536    // edges per level (PP*KK)
#define NLVL 15       // levels with edges

typedef _Float16 h8 __attribute__((ext_vector_type(8)));
typedef _Float16 h4 __attribute__((ext_vector_type(4)));
typedef float f4v __attribute__((ext_vector_type(4)));

__device__ __forceinline__ float4 ld4(const float* p) { return *(const float4*)p; }
__device__ __forceinline__ void st4(float* p, float4 v) { *(float4*)p = v; }

// XOR swizzle for f16 [row][128] arrays read as h8 (ds_read_b128): spreads the
// row-stride-256B pattern across banks (guide G4). Index in halves.
__device__ __forceinline__ int swz(int row, int k) { return row * 128 + (k ^ ((row & 7) << 3)); }
// XOR swizzle for f32 [row][128] scratch written scalar by D-frags, read as float4.
__device__ __forceinline__ int uswz(int row, int c) { return row * 128 + (c ^ ((row & 7) << 2)); }

// Split a float4 into f16 hi/lo and store 4 contiguous (swizzled) halves each.
__device__ __forceinline__ void split_store(_Float16* ah, _Float16* al, int row, int k0, float4 v) {
  int o = swz(row, k0);
  h4 hi, lo;
  _Float16 t0 = (_Float16)v.x; hi[0] = t0; lo[0] = (_Float16)(v.x - (float)t0);
  _Float16 t1 = (_Float16)v.y; hi[1] = t1; lo[1] = (_Float16)(v.y - (float)t1);
  _Float16 t2 = (_Float16)v.z; hi[2] = t2; lo[2] = (_Float16)(v.z - (float)t2);
  _Float16 t3 = (_Float16)v.w; hi[3] = t3; lo[3] = (_Float16)(v.w - (float)t3);
  *(h4*)(ah + o) = hi;
  *(h4*)(al + o) = lo;
}

// One wave computes a 16-row x 64-col output tile of A[rows][128] @ W[128][128]
// via f16-split MFMA (3 passes, fp32 accumulate).
// ah/al: A hi/lo, [rows][128] halves, swizzled. wh/wl: W^T hi/lo images [n][128] swizzled.
// Fragment layouts (guide §3, m89-verified): A-frag lane l holds A[l&15][(l>>4)*8+j];
// B-frag lane l holds Wt[l&15][(l>>4)*8+j]; D lane l reg r -> row (l>>4)*4+r, col l&15.
__device__ __forceinline__ void mfma_gemm(const _Float16* __restrict__ ah, const _Float16* __restrict__ al,
                                          const _Float16* __restrict__ wh, const _Float16* __restrict__ wl,
                                          int rbase, int cb, int lane, f4v acc[4]) {
  int r16 = lane & 15, kb = lane >> 4;
  int arow = rbase + r16;
  h8 A_hi[4], A_lo[4];
#pragma unroll
  for (int ks = 0; ks < 4; ks++) {
    int o = swz(arow, ks * 32 + kb * 8);
    A_hi[ks] = *(const h8*)(ah + o);
    A_lo[ks] = *(const h8*)(al + o);
  }
#pragma unroll
  for (int t = 0; t < 4; t++) {
    int wrow = cb + t * 16 + r16;
    h8 B_hi[4], B_lo[4];
#pragma unroll
    for (int ks = 0; ks < 4; ks++) {
      int o = swz(wrow, ks * 32 + kb * 8);
      B_hi[ks] = *(const h8*)(wh + o);
      B_lo[ks] = *(const h8*)(wl + o);
    }
    f4v a = {0.f, 0.f, 0.f, 0.f};
#pragma unroll
    for (int ks = 0; ks < 4; ks++) a = __builtin_amdgcn_mfma_f32_16x16x32_f16(A_hi[ks], B_hi[ks], a, 0, 0, 0);
#pragma unroll
    for (int ks = 0; ks < 4; ks++) a = __builtin_amdgcn_mfma_f32_16x16x32_f16(A_lo[ks], B_hi[ks], a, 0, 0, 0);
#pragma unroll
    for (int ks = 0; ks < 4; ks++) a = __builtin_amdgcn_mfma_f32_16x16x32_f16(A_hi[ks], B_lo[ks], a, 0, 0, 0);
    acc[t] = a;
  }
}

// ---------------- Weight prep: W[k][n] fp32 -> transposed, split, pre-swizzled f16 image ----
// img layout: hi at [0..16383], lo at [16384..32767]; element (n,k) at n*128 + (k^((n&7)<<3)).
__global__ __launch_bounds__(256) void prep_w(const float* __restrict__ w, _Float16* __restrict__ img) {
  int s4 = blockIdx.x * 256 + threadIdx.x;     // float4 index, grid 16 -> 4096 float4 = 16384 el
  float4 v = ((const float4*)w)[s4];
  int s = s4 * 4;
  int k = s >> 7, n0 = s & 127;
  float a[4] = {v.x, v.y, v.z, v.w};
#pragma unroll
  for (int i = 0; i < 4; i++) {
    int n = n0 + i;
    int o = n * 128 + (k ^ ((n & 7) << 3));
    _Float16 hi = (_Float16)a[i];
    img[o] = hi;
    img[16384 + o] = (_Float16)(a[i] - (float)hi);
  }
}

// ---------------- Node transform: h = relu(x@w1+b1)@w2 + b2 ----------------
// 512 threads (8 waves), 64-row tiles, grid = NN/64 = 2048. LDS 96KB -> 1 block/CU.
__global__ __launch_bounds__(512) void nt_kernel(
    const float* __restrict__ x,
    const _Float16* __restrict__ w1img, const float* __restrict__ b1,
    const _Float16* __restrict__ w2img, const float* __restrict__ b2,
    float* __restrict__ hout) {
  __shared__ __align__(16) _Float16 wsh[32768];  // 64 KB: W^T hi+lo image
  __shared__ __align__(16) float abuf[8192];     // 32 KB: A-splits OR f32 scratch
  _Float16* ah = (_Float16*)abuf;
  _Float16* al = ah + 8192;
  int tid = threadIdx.x;
  int lane = tid & 63, wv = tid >> 6;
  int c4 = tid & 31, rg4 = (tid >> 5) * 4;       // rows 0..60
  size_t base = (size_t)blockIdx.x * 64;

  {
    const float4* wi = (const float4*)w1img;
    float4* wd = (float4*)wsh;
#pragma unroll
    for (int j = 0; j < 8; j++) wd[tid + j * 512] = wi[tid + j * 512];
  }
#pragma unroll
  for (int j = 0; j < 4; j++) {
    int s = tid + j * 512;
    float4 v = ((const float4*)(x + base * 128))[s];
    split_store(ah, al, s >> 5, (s & 31) * 4, v);
  }
  __syncthreads();

  f4v acc[4];
  int rb = (wv & 3) * 16, cbc = (wv >> 2) * 64;
  mfma_gemm(ah, al, wsh, wsh + 16384, rb, cbc, lane, acc);
  __syncthreads();
  {
    int r16 = lane & 15, kb = lane >> 4;
#pragma unroll
    for (int t = 0; t < 4; t++) {
      int col = cbc + t * 16 + r16;
      float b = b1[col];
#pragma unroll
      for (int r = 0; r < 4; r++) abuf[uswz(rb + kb * 4 + r, col)] = fmaxf(acc[t][r] + b, 0.f);
    }
  }
  {
    const float4* wi = (const float4*)w2img;
    float4* wd = (float4*)wsh;
#pragma unroll
    for (int j = 0; j < 8; j++) wd[tid + j * 512] = wi[tid + j * 512];
  }
  __syncthreads();

  float4 uu[4];
#pragma unroll
  for (int i = 0; i < 4; i++) uu[i] = *(const float4*)(abuf + uswz(rg4 + i, c4 * 4));
  __syncthreads();
#pragma unroll
  for (int i = 0; i < 4; i++) split_store(ah, al, rg4 + i, c4 * 4, uu[i]);
  __syncthreads();

  mfma_gemm(ah, al, wsh, wsh + 16384, rb, cbc, lane, acc);
  __syncthreads();
  {
    int r16 = lane & 15, kb = lane >> 4;
#pragma unroll
    for (int t = 0; t < 4; t++) {
      int col = cbc + t * 16 + r16;
      float b = b2[col];
#pragma unroll
      for (int r = 0; r < 4; r++) abuf[uswz(rb + kb * 4 + r, col)] = acc[t][r] + b;
    }
  }
  __syncthreads();
#pragma unroll
  for (int i = 0; i < 4; i++)
    st4(hout + (base + rg4 + i) * 128 + c4 * 4, *(const float4*)(abuf + uswz(rg4 + i, c4 * 4)));
}

// ---------------- CSR build (reverse-edge transpose) ----------------
__global__ __launch_bounds__(256) void csr_count(const int* __restrict__ src_all,
                                                 int* __restrict__ deg) {
  int e = blockIdx.x * 256 + threadIdx.x;  // grid = 3840 -> exactly 15*65536
  int l = e >> 16;
  int q = src_all[e];
  atomicAdd(&deg[l * PP + q], 1);
}

__global__ __launch_bounds__(256) void csr_scan(const int* __restrict__ deg,
                                                int* __restrict__ offs,
                                                int* __restrict__ cursor) {
  int l = blockIdx.x;
  int t = threadIdx.x;
  const int* d = deg + l * PP;
  __shared__ int ssum[256];
  int loc[32];
  int s = 0;
#pragma unroll
  for (int j = 0; j < 32; j++) { loc[j] = d[t * 32 + j]; s += loc[j]; }
  ssum[t] = s;
  __syncthreads();
  for (int off = 1; off < 256; off <<= 1) {
    int v = (t >= off) ? ssum[t - off] : 0;
    __syncthreads();
    ssum[t] += v;
    __syncthreads();
  }
  int run = (t == 0) ? 0 : ssum[t - 1];
#pragma unroll
  for (int j = 0; j < 32; j++) {
    offs[l * (PP + 1) + t * 32 + j] = run;
    cursor[l * PP + t * 32 + j] = run;
    run += loc[j];
  }
  if (t == 255) offs[l * (PP + 1) + PP] = run;
}

__global__ __launch_bounds__(256) void csr_fill(const int* __restrict__ src_all,
                                                int* __restrict__ cursor,
                                                int* __restrict__ edges) {
  int e = blockIdx.x * 256 + threadIdx.x;
  int l = e >> 16;
  int q = src_all[e];
  int pos = atomicAdd(&cursor[l * PP + q], 1);
  edges[l * NE + pos] = (e & (NE - 1)) >> 3;   // dst node p of this fwd edge
}

// ---------------- Fused message-passing step ----------------
// grid = 512: blocks 0..255 = forward level `step`, 256..511 = reverse level 15-step
// 256 threads (4 waves), 32-row tiles. LDS 80KB -> 2 blocks/CU.
__global__ __launch_bounds__(256) void mp_step(
    const float* __restrict__ h,
    const int* __restrict__ src_all,
    const int* __restrict__ offs,
    const int* __restrict__ edges,
    const _Float16* __restrict__ fw_upd_img, const float* __restrict__ fw_upd_b,
    const _Float16* __restrict__ fw_pre_img, const float* __restrict__ fw_pre_b,
    const _Float16* __restrict__ bw_upd_img, const float* __restrict__ bw_upd_b,
    const _Float16* __restrict__ bw_pre_img, const float* __restrict__ bw_pre_b,
    const float* __restrict__ mf_in, float* __restrict__ mf_out,
    const float* __restrict__ mb_in, float* __restrict__ mb_out,
    float* __restrict__ out, int step) {
  __shared__ __align__(16) _Float16 wsh[32768];  // 64 KB weight image
  __shared__ __align__(16) float abuf[4096];     // 16 KB: A-splits OR f32 scratch
  _Float16* ah = (_Float16*)abuf;
  _Float16* al = ah + 4096;
  int tid = threadIdx.x;
  int lane = tid & 63, wv = tid >> 6;
  int c4 = tid & 31, rg4 = (tid >> 5) * 4;       // 0..28
  bool is_fwd = blockIdx.x < 256;
  int tile = (blockIdx.x & 255) * 32;
  int level = is_fwd ? step : 15 - step;
  const _Float16* upd_img = is_fwd ? fw_upd_img : bw_upd_img;
  const float* upd_b = is_fwd ? fw_upd_b : bw_upd_b;
  const _Float16* pre_img = is_fwd ? fw_pre_img : bw_pre_img;
  const float* pre_b = is_fwd ? fw_pre_b : bw_pre_b;
  const float* m_in  = is_fwd ? mf_in : mb_in;
  float* m_out       = is_fwd ? mf_out : mb_out;
  bool has_gather = (step > 0);
  bool has_mout   = (step < 15);
  int col_off = is_fwd ? 0 : 128;
  int rb = (wv & 1) * 16, cbc = (wv >> 1) * 64;

  // stage upd weight image (issued early; overlaps gather latency)
  {
    const float4* wi = (const float4*)upd_img;
    float4* wd = (float4*)wsh;
#pragma unroll
    for (int j = 0; j < 16; j++) wd[tid + j * 256] = wi[tid + j * 256];
  }

  // ---- phase A: gather z, write f16 splits into abuf ----
  if (has_gather) {
    if (is_fwd) {
      const int* src = src_all + (step - 1) * NE;
#pragma unroll
      for (int i = 0; i < 4; i++) {
        int r = rg4 + i;
        int p = tile + r;
        float4 v[8];
#pragma unroll
        for (int k = 0; k < 8; k++) {
          int s = src[p * 8 + k];
          v[k] = ld4(m_in + (size_t)s * 128 + c4 * 4);
        }
        float4 a;
        a.x = ((v[0].x + v[1].x) + (v[2].x + v[3].x)) + ((v[4].x + v[5].x) + (v[6].x + v[7].x));
        a.y = ((v[0].y + v[1].y) + (v[2].y + v[3].y)) + ((v[4].y + v[5].y) + (v[6].y + v[7].y));
        a.z = ((v[0].z + v[1].z) + (v[2].z + v[3].z)) + ((v[4].z + v[5].z) + (v[6].z + v[7].z));
        a.w = ((v[0].w + v[1].w) + (v[2].w + v[3].w)) + ((v[4].w + v[5].w) + (v[6].w + v[7].w));
        a.x *= 0.125f; a.y *= 0.125f; a.z *= 0.125f; a.w *= 0.125f;
        split_store(ah, al, r, c4 * 4, a);
      }
    } else {
      const int* off_l = offs + level * (PP + 1);
      const int* ep = edges + level * NE;
#pragma unroll
      for (int i = 0; i < 4; i++) {
        int r = rg4 + i;
        int q = tile + r;
        int e0 = off_l[q], e1 = off_l[q + 1];
        float4 a = {0.f, 0.f, 0.f, 0.f};
        int idx = e0;
        for (; idx + 4 <= e1; idx += 4) {
          int p0 = ep[idx], p1 = ep[idx + 1], p2 = ep[idx + 2], p3 = ep[idx + 3];
          float4 v0 = ld4(m_in + (size_t)p0 * 128 + c4 * 4);
          float4 v1 = ld4(m_in + (size_t)p1 * 128 + c4 * 4);
          float4 v2 = ld4(m_in + (size_t)p2 * 128 + c4 * 4);
          float4 v3 = ld4(m_in + (size_t)p3 * 128 + c4 * 4);
          a.x += (v0.x + v1.x) + (v2.x + v3.x);
          a.y += (v0.y + v1.y) + (v2.y + v3.y);
          a.z += (v0.z + v1.z) + (v2.z + v3.z);
          a.w += (v0.w + v1.w) + (v2.w + v3.w);
        }
        for (; idx < e1; idx++) {
          int p = ep[idx];
          float4 v = ld4(m_in + (size_t)p * 128 + c4 * 4);
          a.x += v.x; a.y += v.y; a.z += v.z; a.w += v.w;
        }
        float inv = (e1 > e0) ? 1.0f / (float)(e1 - e0) : 0.f;
        a.x *= inv; a.y *= inv; a.z *= inv; a.w *= inv;
        split_store(ah, al, r, c4 * 4, a);
      }
    }
  } else {
    float4 z = {0.f, 0.f, 0.f, 0.f};
#pragma unroll
    for (int i = 0; i < 4; i++) split_store(ah, al, rg4 + i, c4 * 4, z);
  }
  __syncthreads();

  // ---- phase B: relu(z@upd_w + upd_b) via MFMA ----
  f4v acc[4];
  mfma_gemm(ah, al, wsh, wsh + 16384, rb, cbc, lane, acc);
  __syncthreads();
  {
    int r16 = lane & 15, kb = lane >> 4;
#pragma unroll
    for (int t = 0; t < 4; t++) {
      int col = cbc + t * 16 + r16;
      float b = upd_b[col];
#pragma unroll
      for (int r = 0; r < 4; r++) abuf[uswz(rb + kb * 4 + r, col)] = fmaxf(acc[t][r] + b, 0.f);
    }
  }
  if (has_mout) {
    const float4* wi = (const float4*)pre_img;
    float4* wd = (float4*)wsh;
#pragma unroll
    for (int j = 0; j < 16; j++) wd[tid + j * 256] = wi[tid + j * 256];
  }
  __syncthreads();

  // ---- residual add + output write (coalesced) ----
  float4 u[4];
#pragma unroll
  for (int i = 0; i < 4; i++) {
    int r = rg4 + i;
    int n = level * PP + tile + r;
    float4 uv = *(const float4*)(abuf + uswz(r, c4 * 4));
    float4 res = ld4(h + (size_t)n * 128 + c4 * 4);
    u[i].x = uv.x + res.x;
    u[i].y = uv.y + res.y;
    u[i].z = uv.z + res.z;
    u[i].w = uv.w + res.w;
    st4(out + (size_t)n * 256 + col_off + c4 * 4, u[i]);
  }
  __syncthreads();

  // ---- phase C: m_out = relu(u @ pre_w + pre_b) ----
  if (has_mout) {
#pragma unroll
    for (int i = 0; i < 4; i++) split_store(ah, al, rg4 + i, c4 * 4, u[i]);
    __syncthreads();
    mfma_gemm(ah, al, wsh, wsh + 16384, rb, cbc, lane, acc);
    __syncthreads();
    {
      int r16 = lane & 15, kb = lane >> 4;
#pragma unroll
      for (int t = 0; t < 4; t++) {
        int col = cbc + t * 16 + r16;
        float b = pre_b[col];
#pragma unroll
        for (int r = 0; r < 4; r++) abuf[uswz(rb + kb * 4 + r, col)] = fmaxf(acc[t][r] + b, 0.f);
      }
    }
    __syncthreads();
#pragma unroll
    for (int i = 0; i < 4; i++) {
      int r = rg4 + i;
      float4 m = *(const float4*)(abuf + uswz(r, c4 * 4));
      st4(m_out + (size_t)(tile + r) * 128 + c4 * 4, m);
    }
  }
}

extern "C" void kernel_launch(void* const* d_in, const int* in_sizes, int n_in,
                              void* d_out, int out_size, void* d_ws, size_t ws_size,
                              hipStream_t stream) {
  const float* x      = (const float*)d_in[0];
  const int*   src    = (const int*)d_in[1];
  const float* nt_w1  = (const float*)d_in[2];
  const float* nt_b1  = (const float*)d_in[3];
  const float* nt_w2  = (const float*)d_in[4];
  const float* nt_b2  = (const float*)d_in[5];
  const float* f_pre_w = (const float*)d_in[6];
  const float* f_pre_b = (const float*)d_in[7];
  const float* f_upd_w = (const float*)d_in[8];
  const float* f_upd_b = (const float*)d_in[9];
  const float* b_pre_w = (const float*)d_in[10];
  const float* b_pre_b = (const float*)d_in[11];
  const float* b_upd_w = (const float*)d_in[12];
  const float* b_upd_b = (const float*)d_in[13];
  float* out = (float*)d_out;

  float* wsf = (float*)d_ws;
  float* h   = wsf;                                  // NN*DD
  float* mf0 = h + (size_t)NN * DD;                  // PP*DD each
  float* mf1 = mf0 + (size_t)PP * DD;
  float* mb0 = mf1 + (size_t)PP * DD;
  float* mb1 = mb0 + (size_t)PP * DD;
  int* deg    = (int*)(mb1 + (size_t)PP * DD);       // NLVL*PP
  int* offs   = deg + NLVL * PP;                     // NLVL*(PP+1)
  int* cursor = offs + NLVL * (PP + 1);              // NLVL*PP
  int* edges  = cursor + NLVL * PP;                  // NLVL*NE

  // f16 split+transposed+swizzled weight images (32768 halves = 64KB each)
  uintptr_t ip = (uintptr_t)(edges + (size_t)NLVL * NE);
  ip = (ip + 15) & ~(uintptr_t)15;
  _Float16* img = (_Float16*)ip;
  _Float16* i_ntw1 = img;
  _Float16* i_ntw2 = img + 32768;
  _Float16* i_fupd = img + 2 * 32768;
  _Float16* i_fpre = img + 3 * 32768;
  _Float16* i_bupd = img + 4 * 32768;
  _Float16* i_bpre = img + 5 * 32768;

  hipMemsetAsync(deg, 0, (size_t)NLVL * PP * sizeof(int), stream);
  prep_w<<<16, 256, 0, stream>>>(nt_w1, i_ntw1);
  prep_w<<<16, 256, 0, stream>>>(nt_w2, i_ntw2);
  prep_w<<<16, 256, 0, stream>>>(f_upd_w, i_fupd);
  prep_w<<<16, 256, 0, stream>>>(f_pre_w, i_fpre);
  prep_w<<<16, 256, 0, stream>>>(b_upd_w, i_bupd);
  prep_w<<<16, 256, 0, stream>>>(b_pre_w, i_bpre);

  nt_kernel<<<NN / 64, 512, 0, stream>>>(x, i_ntw1, nt_b1, i_ntw2, nt_b2, h);
  csr_count<<<NLVL * NE / 256, 256, 0, stream>>>(src, deg);
  csr_scan<<<NLVL, 256, 0, stream>>>(deg, offs, cursor);
  csr_fill<<<NLVL * NE / 256, 256, 0, stream>>>(src, cursor, edges);

  for (int s = 0; s < 16; s++) {
    const float* mf_in = (s & 1) ? mf0 : mf1;
    float* mf_out      = (s & 1) ? mf1 : mf0;
    const float* mb_in = (s & 1) ? mb0 : mb1;
    float* mb_out      = (s & 1) ? mb1 : mb0;
    mp_step<<<512, 256, 0, stream>>>(h, src, offs, edges,
                                     i_fupd, f_upd_b, i_fpre, f_pre_b,
                                     i_bupd, b_upd_b, i_bpre, b_pre_b,
                                     mf_in, mf_out, mb_in, mb_out, out, s);
  }
}

// Round 3
// 616.836 us; speedup vs baseline: 1.6096x; 1.1295x over previous
//
#include <hip/hip_runtime.h>
#include <cstddef>
#include <cstdint>

// Problem constants (fixed-shape problem)
#define DD   128      // feature dim
#define PP   8192     // nodes per level
#define KK   8        // in-edges per node
#define LLV  16       // levels
#define NN   131072   // total nodes
#define NE   65536    // edges per level (PP*KK)
#define NLVL 15       // levels with edges

typedef _Float16 h8 __attribute__((ext_vector_type(8)));
typedef _Float16 h4 __attribute__((ext_vector_type(4)));
typedef float f4v __attribute__((ext_vector_type(4)));

__device__ __forceinline__ float4 ld4(const float* p) { return *(const float4*)p; }
__device__ __forceinline__ void st4(float* p, float4 v) { *(float4*)p = v; }

// XOR swizzle for f16 [row][128] LDS arrays read as h8 (ds_read_b128): consecutive
// rows shift by 16B so each 16-lane group covers all 32 banks (2-way = free).
__device__ __forceinline__ int swz(int row, int k) { return row * 128 + (k ^ ((row & 7) << 3)); }
// XOR swizzle for f32 [row][128] scratch written scalar by D-frags, read as float4.
__device__ __forceinline__ int uswz(int row, int c) { return row * 128 + (c ^ ((row & 7) << 2)); }

// Split a float4 into f16 hi/lo and store 4 contiguous (swizzled) halves each.
__device__ __forceinline__ void split_store(_Float16* ah, _Float16* al, int row, int k0, float4 v) {
  int o = swz(row, k0);
  h4 hi, lo;
  _Float16 t0 = (_Float16)v.x; hi[0] = t0; lo[0] = (_Float16)(v.x - (float)t0);
  _Float16 t1 = (_Float16)v.y; hi[1] = t1; lo[1] = (_Float16)(v.y - (float)t1);
  _Float16 t2 = (_Float16)v.z; hi[2] = t2; lo[2] = (_Float16)(v.z - (float)t2);
  _Float16 t3 = (_Float16)v.w; hi[3] = t3; lo[3] = (_Float16)(v.w - (float)t3);
  *(h4*)(ah + o) = hi;
  *(h4*)(al + o) = lo;
}

// Load B-fragments for one 32-col strip (2 col-tiles x 4 k-slices, hi+lo) from the
// fragment-ordered global image: 16 fully-coalesced global_load_dwordx4 -> 64 VGPRs.
__device__ __forceinline__ void load_bfrags(const _Float16* __restrict__ img, int cs, int lane,
                                            h8 Bh[2][4], h8 Bl[2][4]) {
#pragma unroll
  for (int ct = 0; ct < 2; ct++) {
    int t16 = cs * 2 + ct;
#pragma unroll
    for (int ks = 0; ks < 4; ks++) {
      int o = ((t16 * 4 + ks) * 64 + lane) * 8;
      Bh[ct][ks] = *(const h8*)(img + o);
      Bl[ct][ks] = *(const h8*)(img + 16384 + o);
    }
  }
}

// 16-row x 32-col output tile: A from swizzled LDS splits, B from registers.
// 3-pass f16 split (hi*hi + lo*hi + hi*lo), fp32 accumulate.
__device__ __forceinline__ void gemm_regB(const _Float16* __restrict__ ah, const _Float16* __restrict__ al,
                                          const h8 Bh[2][4], const h8 Bl[2][4],
                                          int rbase, int lane, f4v acc[2]) {
  int r16 = lane & 15, kb = lane >> 4;
  int arow = rbase + r16;
  h8 Ah[4], Al[4];
#pragma unroll
  for (int ks = 0; ks < 4; ks++) {
    int o = swz(arow, ks * 32 + kb * 8);
    Ah[ks] = *(const h8*)(ah + o);
    Al[ks] = *(const h8*)(al + o);
  }
#pragma unroll
  for (int ct = 0; ct < 2; ct++) {
    f4v a = {0.f, 0.f, 0.f, 0.f};
#pragma unroll
    for (int ks = 0; ks < 4; ks++) a = __builtin_amdgcn_mfma_f32_16x16x32_f16(Ah[ks], Bh[ct][ks], a, 0, 0, 0);
#pragma unroll
    for (int ks = 0; ks < 4; ks++) a = __builtin_amdgcn_mfma_f32_16x16x32_f16(Al[ks], Bh[ct][ks], a, 0, 0, 0);
#pragma unroll
    for (int ks = 0; ks < 4; ks++) a = __builtin_amdgcn_mfma_f32_16x16x32_f16(Ah[ks], Bl[ct][ks], a, 0, 0, 0);
    acc[ct] = a;
  }
}

// ---------------- Weight prep: W[k][n] fp32 -> fragment-ordered f16 hi/lo image ----
// For (t16, ks, lane): h8 = W[ks*32 + (lane>>4)*8 + j][t16*16 + (lane&15)], j=0..7.
// hi at ((t16*4+ks)*64+lane)*8, lo at +16384. All 6 matrices in one launch (grid 48).
__global__ __launch_bounds__(256) void prep_all(
    const float* __restrict__ w0, const float* __restrict__ w1,
    const float* __restrict__ w2, const float* __restrict__ w3,
    const float* __restrict__ w4, const float* __restrict__ w5,
    _Float16* __restrict__ img_base) {
  int mat = blockIdx.x >> 3;
  int g = (blockIdx.x & 7) * 256 + threadIdx.x;   // 0..2047
  const float* w;
  switch (mat) {
    case 0: w = w0; break;
    case 1: w = w1; break;
    case 2: w = w2; break;
    case 3: w = w3; break;
    case 4: w = w4; break;
    default: w = w5; break;
  }
  _Float16* img = img_base + (size_t)mat * 32768;
  int t16 = g >> 8, ks = (g >> 6) & 3, lane = g & 63;
  int n = t16 * 16 + (lane & 15);
  int kb = ks * 32 + (lane >> 4) * 8;
  h8 hi, lo;
#pragma unroll
  for (int j = 0; j < 8; j++) {
    float v = w[(kb + j) * 128 + n];
    _Float16 h = (_Float16)v;
    hi[j] = h;
    lo[j] = (_Float16)(v - (float)h);
  }
  int o = ((t16 * 4 + ks) * 64 + lane) * 8;
  *(h8*)(img + o) = hi;
  *(h8*)(img + 16384 + o) = lo;
}

// ---------------- Node transform: h = relu(x@w1+b1)@w2 + b2 ----------------
// 512 threads (8 waves = 2 row-halves x 4 col-strips), 64-row tiles, grid 2048.
__global__ __launch_bounds__(512, 3) void nt_kernel(
    const float* __restrict__ x,
    const _Float16* __restrict__ w1img, const float* __restrict__ b1,
    const _Float16* __restrict__ w2img, const float* __restrict__ b2,
    float* __restrict__ hout) {
  __shared__ __align__(16) float abuf[8192];     // 32 KB: A-splits OR f32 scratch
  _Float16* ah = (_Float16*)abuf;
  _Float16* al = ah + 8192;
  int tid = threadIdx.x;
  int lane = tid & 63, wv = tid >> 6;
  int c4 = tid & 31, rg4 = (tid >> 5) * 4;       // rows 0..60
  int cs = wv & 3, rh = (wv >> 2) * 32;          // col strip, row half (2 tiles)
  size_t base = (size_t)blockIdx.x * 64;

  h8 Bh[2][4], Bl[2][4];
  load_bfrags(w1img, cs, lane, Bh, Bl);

#pragma unroll
  for (int j = 0; j < 4; j++) {
    int s = tid + j * 512;
    float4 v = ((const float4*)(x + base * 128))[s];
    split_store(ah, al, s >> 5, (s & 31) * 4, v);
  }
  __syncthreads();

  f4v acc[2][2];
#pragma unroll
  for (int rt = 0; rt < 2; rt++) gemm_regB(ah, al, Bh, Bl, rh + rt * 16, lane, acc[rt]);
  load_bfrags(w2img, cs, lane, Bh, Bl);
  __syncthreads();
  {
    int r16 = lane & 15, kb = lane >> 4;
#pragma unroll
    for (int rt = 0; rt < 2; rt++)
#pragma unroll
      for (int ct = 0; ct < 2; ct++) {
        int col = cs * 32 + ct * 16 + r16;
        float b = b1[col];
#pragma unroll
        for (int r = 0; r < 4; r++)
          abuf[uswz(rh + rt * 16 + kb * 4 + r, col)] = fmaxf(acc[rt][ct][r] + b, 0.f);
      }
  }
  __syncthreads();

  float4 uu[4];
#pragma unroll
  for (int i = 0; i < 4; i++) uu[i] = *(const float4*)(abuf + uswz(rg4 + i, c4 * 4));
  __syncthreads();
#pragma unroll
  for (int i = 0; i < 4; i++) split_store(ah, al, rg4 + i, c4 * 4, uu[i]);
  __syncthreads();

#pragma unroll
  for (int rt = 0; rt < 2; rt++) gemm_regB(ah, al, Bh, Bl, rh + rt * 16, lane, acc[rt]);
  __syncthreads();
  {
    int r16 = lane & 15, kb = lane >> 4;
#pragma unroll
    for (int rt = 0; rt < 2; rt++)
#pragma unroll
      for (int ct = 0; ct < 2; ct++) {
        int col = cs * 32 + ct * 16 + r16;
        float b = b2[col];
#pragma unroll
        for (int r = 0; r < 4; r++)
          abuf[uswz(rh + rt * 16 + kb * 4 + r, col)] = acc[rt][ct][r] + b;
      }
  }
  __syncthreads();
#pragma unroll
  for (int i = 0; i < 4; i++)
    st4(hout + (base + rg4 + i) * 128 + c4 * 4, *(const float4*)(abuf + uswz(rg4 + i, c4 * 4)));
}

// ---------------- CSR build (reverse-edge transpose) ----------------
__global__ __launch_bounds__(256) void csr_count(const int* __restrict__ src_all,
                                                 int* __restrict__ deg) {
  int e = blockIdx.x * 256 + threadIdx.x;  // grid = 3840 -> exactly 15*65536
  int l = e >> 16;
  int q = src_all[e];
  atomicAdd(&deg[l * PP + q], 1);
}

__global__ __launch_bounds__(256) void csr_scan(const int* __restrict__ deg,
                                                int* __restrict__ offs,
                                                int* __restrict__ cursor) {
  int l = blockIdx.x;
  int t = threadIdx.x;
  const int* d = deg + l * PP;
  __shared__ int ssum[256];
  int loc[32];
  int s = 0;
#pragma unroll
  for (int j = 0; j < 32; j++) { loc[j] = d[t * 32 + j]; s += loc[j]; }
  ssum[t] = s;
  __syncthreads();
  for (int off = 1; off < 256; off <<= 1) {
    int v = (t >= off) ? ssum[t - off] : 0;
    __syncthreads();
    ssum[t] += v;
    __syncthreads();
  }
  int run = (t == 0) ? 0 : ssum[t - 1];
#pragma unroll
  for (int j = 0; j < 32; j++) {
    offs[l * (PP + 1) + t * 32 + j] = run;
    cursor[l * PP + t * 32 + j] = run;
    run += loc[j];
  }
  if (t == 255) offs[l * (PP + 1) + PP] = run;
}

__global__ __launch_bounds__(256) void csr_fill(const int* __restrict__ src_all,
                                                int* __restrict__ cursor,
                                                int* __restrict__ edges) {
  int e = blockIdx.x * 256 + threadIdx.x;
  int l = e >> 16;
  int q = src_all[e];
  int pos = atomicAdd(&cursor[l * PP + q], 1);
  edges[l * NE + pos] = (e & (NE - 1)) >> 3;   // dst node p of this fwd edge
}

// ---------------- Fused message-passing step ----------------
// grid = 512: blocks 0..255 = forward level `step`, 256..511 = reverse level 15-step
// 512 threads (8 waves = 2 row-halves x 4 col-strips), 32-row tiles. LDS 16 KB.
__global__ __launch_bounds__(512, 4) void mp_step(
    const float* __restrict__ h,
    const int* __restrict__ src_all,
    const int* __restrict__ offs,
    const int* __restrict__ edges,
    const _Float16* __restrict__ fw_upd_img, const float* __restrict__ fw_upd_b,
    const _Float16* __restrict__ fw_pre_img, const float* __restrict__ fw_pre_b,
    const _Float16* __restrict__ bw_upd_img, const float* __restrict__ bw_upd_b,
    const _Float16* __restrict__ bw_pre_img, const float* __restrict__ bw_pre_b,
    const float* __restrict__ mf_in, float* __restrict__ mf_out,
    const float* __restrict__ mb_in, float* __restrict__ mb_out,
    float* __restrict__ out, int step) {
  __shared__ __align__(16) float abuf[4096];     // 16 KB: A-splits OR f32 scratch
  _Float16* ah = (_Float16*)abuf;
  _Float16* al = ah + 4096;
  int tid = threadIdx.x;
  int lane = tid & 63, wv = tid >> 6;
  int c4 = tid & 31, rg2 = (tid >> 5) * 2;       // rows 0..30, 2 per thread
  int cs = wv & 3, rh = (wv >> 2) * 16;          // col strip, row half (1 tile)
  bool is_fwd = blockIdx.x < 256;
  int tile = (blockIdx.x & 255) * 32;
  int level = is_fwd ? step : 15 - step;
  const _Float16* upd_img = is_fwd ? fw_upd_img : bw_upd_img;
  const float* upd_b = is_fwd ? fw_upd_b : bw_upd_b;
  const _Float16* pre_img = is_fwd ? fw_pre_img : bw_pre_img;
  const float* pre_b = is_fwd ? fw_pre_b : bw_pre_b;
  const float* m_in  = is_fwd ? mf_in : mb_in;
  float* m_out       = is_fwd ? mf_out : mb_out;
  bool has_gather = (step > 0);
  bool has_mout   = (step < 15);
  int col_off = is_fwd ? 0 : 128;

  // B-fragments for the update GEMM: issued first, latency overlaps the gather.
  h8 Bh[2][4], Bl[2][4];
  load_bfrags(upd_img, cs, lane, Bh, Bl);

  // ---- phase A: gather z, write f16 splits into abuf ----
  if (has_gather) {
    if (is_fwd) {
      const int* src = src_all + (step - 1) * NE;
#pragma unroll
      for (int i = 0; i < 2; i++) {
        int r = rg2 + i;
        int p = tile + r;
        float4 v[8];
#pragma unroll
        for (int k = 0; k < 8; k++) {
          int s = src[p * 8 + k];
          v[k] = ld4(m_in + (size_t)s * 128 + c4 * 4);
        }
        float4 a;
        a.x = ((v[0].x + v[1].x) + (v[2].x + v[3].x)) + ((v[4].x + v[5].x) + (v[6].x + v[7].x));
        a.y = ((v[0].y + v[1].y) + (v[2].y + v[3].y)) + ((v[4].y + v[5].y) + (v[6].y + v[7].y));
        a.z = ((v[0].z + v[1].z) + (v[2].z + v[3].z)) + ((v[4].z + v[5].z) + (v[6].z + v[7].z));
        a.w = ((v[0].w + v[1].w) + (v[2].w + v[3].w)) + ((v[4].w + v[5].w) + (v[6].w + v[7].w));
        a.x *= 0.125f; a.y *= 0.125f; a.z *= 0.125f; a.w *= 0.125f;
        split_store(ah, al, r, c4 * 4, a);
      }
    } else {
      const int* off_l = offs + level * (PP + 1);
      const int* ep = edges + level * NE;
#pragma unroll
      for (int i = 0; i < 2; i++) {
        int r = rg2 + i;
        int q = tile + r;
        int e0 = off_l[q], e1 = off_l[q + 1];
        float4 a = {0.f, 0.f, 0.f, 0.f};
        int idx = e0;
        for (; idx + 4 <= e1; idx += 4) {
          int p0 = ep[idx], p1 = ep[idx + 1], p2 = ep[idx + 2], p3 = ep[idx + 3];
          float4 v0 = ld4(m_in + (size_t)p0 * 128 + c4 * 4);
          float4 v1 = ld4(m_in + (size_t)p1 * 128 + c4 * 4);
          float4 v2 = ld4(m_in + (size_t)p2 * 128 + c4 * 4);
          float4 v3 = ld4(m_in + (size_t)p3 * 128 + c4 * 4);
          a.x += (v0.x + v1.x) + (v2.x + v3.x);
          a.y += (v0.y + v1.y) + (v2.y + v3.y);
          a.z += (v0.z + v1.z) + (v2.z + v3.z);
          a.w += (v0.w + v1.w) + (v2.w + v3.w);
        }
        for (; idx < e1; idx++) {
          int p = ep[idx];
          float4 v = ld4(m_in + (size_t)p * 128 + c4 * 4);
          a.x += v.x; a.y += v.y; a.z += v.z; a.w += v.w;
        }
        float inv = (e1 > e0) ? 1.0f / (float)(e1 - e0) : 0.f;
        a.x *= inv; a.y *= inv; a.z *= inv; a.w *= inv;
        split_store(ah, al, r, c4 * 4, a);
      }
    }
  } else {
    float4 z = {0.f, 0.f, 0.f, 0.f};
#pragma unroll
    for (int i = 0; i < 2; i++) split_store(ah, al, rg2 + i, c4 * 4, z);
  }
  __syncthreads();

  // ---- phase B: relu(z@upd_w + upd_b) via MFMA (B in registers) ----
  f4v acc[2];
  gemm_regB(ah, al, Bh, Bl, rh, lane, acc);
  __syncthreads();                      // all A-frag reads done before scratch overwrite
  {
    int r16 = lane & 15, kb = lane >> 4;
#pragma unroll
    for (int ct = 0; ct < 2; ct++) {
      int col = cs * 32 + ct * 16 + r16;
      float b = upd_b[col];
#pragma unroll
      for (int r = 0; r < 4; r++) abuf[uswz(rh + kb * 4 + r, col)] = fmaxf(acc[ct][r] + b, 0.f);
    }
  }
  if (has_mout) load_bfrags(pre_img, cs, lane, Bh, Bl);   // overlaps next phases
  __syncthreads();

  // ---- residual add + output write (coalesced) ----
  float4 u[2];
#pragma unroll
  for (int i = 0; i < 2; i++) {
    int r = rg2 + i;
    int n = level * PP + tile + r;
    float4 uv = *(const float4*)(abuf + uswz(r, c4 * 4));
    float4 res = ld4(h + (size_t)n * 128 + c4 * 4);
    u[i].x = uv.x + res.x;
    u[i].y = uv.y + res.y;
    u[i].z = uv.z + res.z;
    u[i].w = uv.w + res.w;
    st4(out + (size_t)n * 256 + col_off + c4 * 4, u[i]);
  }
  __syncthreads();

  // ---- phase C: m_out = relu(u @ pre_w + pre_b) ----
  if (has_mout) {
#pragma unroll
    for (int i = 0; i < 2; i++) split_store(ah, al, rg2 + i, c4 * 4, u[i]);
    __syncthreads();
    gemm_regB(ah, al, Bh, Bl, rh, lane, acc);
    __syncthreads();
    {
      int r16 = lane & 15, kb = lane >> 4;
#pragma unroll
      for (int ct = 0; ct < 2; ct++) {
        int col = cs * 32 + ct * 16 + r16;
        float b = pre_b[col];
#pragma unroll
        for (int r = 0; r < 4; r++) abuf[uswz(rh + kb * 4 + r, col)] = fmaxf(acc[ct][r] + b, 0.f);
      }
    }
    __syncthreads();
#pragma unroll
    for (int i = 0; i < 2; i++) {
      int r = rg2 + i;
      float4 m = *(const float4*)(abuf + uswz(r, c4 * 4));
      st4(m_out + (size_t)(tile + r) * 128 + c4 * 4, m);
    }
  }
}

extern "C" void kernel_launch(void* const* d_in, const int* in_sizes, int n_in,
                              void* d_out, int out_size, void* d_ws, size_t ws_size,
                              hipStream_t stream) {
  const float* x      = (const float*)d_in[0];
  const int*   src    = (const int*)d_in[1];
  const float* nt_w1  = (const float*)d_in[2];
  const float* nt_b1  = (const float*)d_in[3];
  const float* nt_w2  = (const float*)d_in[4];
  const float* nt_b2  = (const float*)d_in[5];
  const float* f_pre_w = (const float*)d_in[6];
  const float* f_pre_b = (const float*)d_in[7];
  const float* f_upd_w = (const float*)d_in[8];
  const float* f_upd_b = (const float*)d_in[9];
  const float* b_pre_w = (const float*)d_in[10];
  const float* b_pre_b = (const float*)d_in[11];
  const float* b_upd_w = (const float*)d_in[12];
  const float* b_upd_b = (const float*)d_in[13];
  float* out = (float*)d_out;

  float* wsf = (float*)d_ws;
  float* h   = wsf;                                  // NN*DD
  float* mf0 = h + (size_t)NN * DD;                  // PP*DD each
  float* mf1 = mf0 + (size_t)PP * DD;
  float* mb0 = mf1 + (size_t)PP * DD;
  float* mb1 = mb0 + (size_t)PP * DD;
  int* deg    = (int*)(mb1 + (size_t)PP * DD);       // NLVL*PP
  int* offs   = deg + NLVL * PP;                     // NLVL*(PP+1)
  int* cursor = offs + NLVL * (PP + 1);              // NLVL*PP
  int* edges  = cursor + NLVL * PP;                  // NLVL*NE

  // fragment-ordered f16 hi/lo weight images (32768 halves = 64KB each)
  uintptr_t ip = (uintptr_t)(edges + (size_t)NLVL * NE);
  ip = (ip + 15) & ~(uintptr_t)15;
  _Float16* img = (_Float16*)ip;
  _Float16* i_ntw1 = img;                 // mat 0
  _Float16* i_ntw2 = img + 32768;         // mat 1
  _Float16* i_fupd = img + 2 * 32768;     // mat 2
  _Float16* i_fpre = img + 3 * 32768;     // mat 3
  _Float16* i_bupd = img + 4 * 32768;     // mat 4
  _Float16* i_bpre = img + 5 * 32768;     // mat 5

  hipMemsetAsync(deg, 0, (size_t)NLVL * PP * sizeof(int), stream);
  prep_all<<<48, 256, 0, stream>>>(nt_w1, nt_w2, f_upd_w, f_pre_w, b_upd_w, b_pre_w, img);

  nt_kernel<<<NN / 64, 512, 0, stream>>>(x, i_ntw1, nt_b1, i_ntw2, nt_b2, h);
  csr_count<<<NLVL * NE / 256, 256, 0, stream>>>(src, deg);
  csr_scan<<<NLVL, 256, 0, stream>>>(deg, offs, cursor);
  csr_fill<<<NLVL * NE / 256, 256, 0, stream>>>(src, cursor, edges);

  for (int s = 0; s < 16; s++) {
    const float* mf_in = (s & 1) ? mf0 : mf1;
    float* mf_out      = (s & 1) ? mf1 : mf0;
    const float* mb_in = (s & 1) ? mb0 : mb1;
    float* mb_out      = (s & 1) ? mb1 : mb0;
    mp_step<<<512, 512, 0, stream>>>(h, src, offs, edges,
                                     i_fupd, f_upd_b, i_fpre, f_pre_b,
                                     i_bupd, b_upd_b, i_bpre, b_pre_b,
                                     mf_in, mf_out, mb_in, mb_out, out, s);
  }
}

// Round 4
// 578.390 us; speedup vs baseline: 1.7166x; 1.0665x over previous
//
#include <hip/hip_runtime.h>
#include <cstddef>
#include <cstdint>

// Problem constants (fixed-shape problem)
#define DD   128      // feature dim
#define PP   8192     // nodes per level
#define KK   8        // in-edges per node
#define LLV  16       // levels
#define NN   131072   // total nodes
#define NE   65536    // edges per level (PP*KK)
#define NLVL 15       // levels with edges

typedef _Float16 h8 __attribute__((ext_vector_type(8)));
typedef _Float16 h4 __attribute__((ext_vector_type(4)));
typedef float f4v __attribute__((ext_vector_type(4)));

__device__ __forceinline__ float4 ld4(const float* p) { return *(const float4*)p; }
__device__ __forceinline__ void st4(float* p, float4 v) { *(float4*)p = v; }

// XOR swizzle for f16 [row][128] LDS arrays read as h8 (ds_read_b128): consecutive
// rows shift by 16B so each 16-lane group covers all 32 banks.
__device__ __forceinline__ int swz(int row, int k) { return row * 128 + (k ^ ((row & 7) << 3)); }
// XOR swizzle for f32 [row][128] scratch written scalar by D-frags, read as float4.
__device__ __forceinline__ int uswz(int row, int c) { return row * 128 + (c ^ ((row & 7) << 2)); }

// Split a float4 into f16 hi/lo and store 4 contiguous (swizzled) halves each.
__device__ __forceinline__ void split_store(_Float16* ah, _Float16* al, int row, int k0, float4 v) {
  int o = swz(row, k0);
  h4 hi, lo;
  _Float16 t0 = (_Float16)v.x; hi[0] = t0; lo[0] = (_Float16)(v.x - (float)t0);
  _Float16 t1 = (_Float16)v.y; hi[1] = t1; lo[1] = (_Float16)(v.y - (float)t1);
  _Float16 t2 = (_Float16)v.z; hi[2] = t2; lo[2] = (_Float16)(v.z - (float)t2);
  _Float16 t3 = (_Float16)v.w; hi[3] = t3; lo[3] = (_Float16)(v.w - (float)t3);
  *(h4*)(ah + o) = hi;
  *(h4*)(al + o) = lo;
}

// Load B-fragments for ONE 16-col tile (4 k-slices, hi+lo): 8 coalesced
// global_load_dwordx4 -> 32 VGPRs. L2-hot (same 64KB image for all blocks).
__device__ __forceinline__ void load_bfrags1(const _Float16* __restrict__ img, int t16, int lane,
                                             h8 Bh[4], h8 Bl[4]) {
#pragma unroll
  for (int ks = 0; ks < 4; ks++) {
    int o = ((t16 * 4 + ks) * 64 + lane) * 8;
    Bh[ks] = *(const h8*)(img + o);
    Bl[ks] = *(const h8*)(img + 16384 + o);
  }
}

// One 16-row x 16-col output tile: A from swizzled LDS splits, B from registers.
// 3-pass f16 split (hi*hi + lo*hi + hi*lo), fp32 accumulate.
__device__ __forceinline__ f4v gemm_rt(const _Float16* __restrict__ ah, const _Float16* __restrict__ al,
                                       const h8 Bh[4], const h8 Bl[4], int rbase, int lane) {
  int r16 = lane & 15, kb = lane >> 4;
  int arow = rbase + r16;
  h8 Ah[4], Al[4];
#pragma unroll
  for (int ks = 0; ks < 4; ks++) {
    int o = swz(arow, ks * 32 + kb * 8);
    Ah[ks] = *(const h8*)(ah + o);
    Al[ks] = *(const h8*)(al + o);
  }
  f4v a = {0.f, 0.f, 0.f, 0.f};
#pragma unroll
  for (int ks = 0; ks < 4; ks++) a = __builtin_amdgcn_mfma_f32_16x16x32_f16(Ah[ks], Bh[ks], a, 0, 0, 0);
#pragma unroll
  for (int ks = 0; ks < 4; ks++) a = __builtin_amdgcn_mfma_f32_16x16x32_f16(Al[ks], Bh[ks], a, 0, 0, 0);
#pragma unroll
  for (int ks = 0; ks < 4; ks++) a = __builtin_amdgcn_mfma_f32_16x16x32_f16(Ah[ks], Bl[ks], a, 0, 0, 0);
  return a;
}

// ---------------- Weight prep: W[k][n] fp32 -> fragment-ordered f16 hi/lo image ----
// For (t16, ks, lane): h8 = W[ks*32 + (lane>>4)*8 + j][t16*16 + (lane&15)], j=0..7.
// hi at ((t16*4+ks)*64+lane)*8, lo at +16384. All 6 matrices in one launch (grid 48).
__global__ __launch_bounds__(256) void prep_all(
    const float* __restrict__ w0, const float* __restrict__ w1,
    const float* __restrict__ w2, const float* __restrict__ w3,
    const float* __restrict__ w4, const float* __restrict__ w5,
    _Float16* __restrict__ img_base) {
  int mat = blockIdx.x >> 3;
  int g = (blockIdx.x & 7) * 256 + threadIdx.x;   // 0..2047
  const float* w;
  switch (mat) {
    case 0: w = w0; break;
    case 1: w = w1; break;
    case 2: w = w2; break;
    case 3: w = w3; break;
    case 4: w = w4; break;
    default: w = w5; break;
  }
  _Float16* img = img_base + (size_t)mat * 32768;
  int t16 = g >> 8, ks = (g >> 6) & 3, lane = g & 63;
  int n = t16 * 16 + (lane & 15);
  int kb = ks * 32 + (lane >> 4) * 8;
  h8 hi, lo;
#pragma unroll
  for (int j = 0; j < 8; j++) {
    float v = w[(kb + j) * 128 + n];
    _Float16 h = (_Float16)v;
    hi[j] = h;
    lo[j] = (_Float16)(v - (float)h);
  }
  int o = ((t16 * 4 + ks) * 64 + lane) * 8;
  *(h8*)(img + o) = hi;
  *(h8*)(img + 16384 + o) = lo;
}

// ---------------- Node transform: h = relu(x@w1+b1)@w2 + b2 ----------------
// 512 threads (8 waves = 8 col-strips of 16), 64-row tiles, grid 2048.
// Separate A-region / D-scratch LDS -> 4 barriers. VGPR peak ~95 under (512,4) cap.
__global__ __launch_bounds__(512, 4) void nt_kernel(
    const float* __restrict__ x,
    const _Float16* __restrict__ w1img, const float* __restrict__ b1,
    const _Float16* __restrict__ w2img, const float* __restrict__ b2,
    float* __restrict__ hout) {
  __shared__ __align__(16) _Float16 asplit[16384];  // 32 KB: hi [0..8191], lo [8192..]
  __shared__ __align__(16) float dbuf[8192];        // 32 KB D-scratch
  _Float16* ah = asplit;
  _Float16* al = asplit + 8192;
  int tid = threadIdx.x;
  int lane = tid & 63, wv = tid >> 6;               // wv = col-tile 0..7
  int c4 = tid & 31, rg4 = (tid >> 5) * 4;          // rows 0..60
  size_t base = (size_t)blockIdx.x * 64;

  h8 Bh[4], Bl[4];
  load_bfrags1(w1img, wv, lane, Bh, Bl);

#pragma unroll
  for (int j = 0; j < 4; j++) {
    int s = tid + j * 512;
    float4 v = ((const float4*)(x + base * 128))[s];
    split_store(ah, al, s >> 5, (s & 31) * 4, v);
  }
  __syncthreads();

  f4v acc[4];
#pragma unroll
  for (int rt = 0; rt < 4; rt++) acc[rt] = gemm_rt(ah, al, Bh, Bl, rt * 16, lane);
  {
    int r16 = lane & 15, kb = lane >> 4;
    int col = wv * 16 + r16;
    float b = b1[col];
#pragma unroll
    for (int rt = 0; rt < 4; rt++)
#pragma unroll
      for (int r = 0; r < 4; r++)
        dbuf[uswz(rt * 16 + kb * 4 + r, col)] = fmaxf(acc[rt][r] + b, 0.f);
  }
  load_bfrags1(w2img, wv, lane, Bh, Bl);
  __syncthreads();

  float4 uu[4];
#pragma unroll
  for (int i = 0; i < 4; i++) uu[i] = *(const float4*)(dbuf + uswz(rg4 + i, c4 * 4));
#pragma unroll
  for (int i = 0; i < 4; i++) split_store(ah, al, rg4 + i, c4 * 4, uu[i]);
  __syncthreads();

#pragma unroll
  for (int rt = 0; rt < 4; rt++) acc[rt] = gemm_rt(ah, al, Bh, Bl, rt * 16, lane);
  {
    int r16 = lane & 15, kb = lane >> 4;
    int col = wv * 16 + r16;
    float b = b2[col];
#pragma unroll
    for (int rt = 0; rt < 4; rt++)
#pragma unroll
      for (int r = 0; r < 4; r++)
        dbuf[uswz(rt * 16 + kb * 4 + r, col)] = acc[rt][r] + b;
  }
  __syncthreads();
#pragma unroll
  for (int i = 0; i < 4; i++)
    st4(hout + (base + rg4 + i) * 128 + c4 * 4, *(const float4*)(dbuf + uswz(rg4 + i, c4 * 4)));
}

// ---------------- CSR build (reverse-edge transpose) ----------------
__global__ __launch_bounds__(256) void csr_count(const int* __restrict__ src_all,
                                                 int* __restrict__ deg) {
  int e = blockIdx.x * 256 + threadIdx.x;  // grid = 3840 -> exactly 15*65536
  int l = e >> 16;
  int q = src_all[e];
  atomicAdd(&deg[l * PP + q], 1);
}

__global__ __launch_bounds__(256) void csr_scan(const int* __restrict__ deg,
                                                int* __restrict__ offs,
                                                int* __restrict__ cursor) {
  int l = blockIdx.x;
  int t = threadIdx.x;
  const int* d = deg + l * PP;
  __shared__ int ssum[256];
  int loc[32];
  int s = 0;
#pragma unroll
  for (int j = 0; j < 32; j++) { loc[j] = d[t * 32 + j]; s += loc[j]; }
  ssum[t] = s;
  __syncthreads();
  for (int off = 1; off < 256; off <<= 1) {
    int v = (t >= off) ? ssum[t - off] : 0;
    __syncthreads();
    ssum[t] += v;
    __syncthreads();
  }
  int run = (t == 0) ? 0 : ssum[t - 1];
#pragma unroll
  for (int j = 0; j < 32; j++) {
    offs[l * (PP + 1) + t * 32 + j] = run;
    cursor[l * PP + t * 32 + j] = run;
    run += loc[j];
  }
  if (t == 255) offs[l * (PP + 1) + PP] = run;
}

__global__ __launch_bounds__(256) void csr_fill(const int* __restrict__ src_all,
                                                int* __restrict__ cursor,
                                                int* __restrict__ edges) {
  int e = blockIdx.x * 256 + threadIdx.x;
  int l = e >> 16;
  int q = src_all[e];
  int pos = atomicAdd(&cursor[l * PP + q], 1);
  edges[l * NE + pos] = (e & (NE - 1)) >> 3;   // dst node p of this fwd edge
}

// ---------------- Fused message-passing step ----------------
// grid = 512: blocks 0..255 = forward level `step`, 256..511 = reverse level 15-step
// 512 threads (8 waves = 8 col-strips of 16), 32-row tiles.
// LDS 32 KB (16 A + 16 D) -> 2 blocks/CU at (512,4); VGPR peak ~90, spill-free.
__global__ __launch_bounds__(512, 4) void mp_step(
    const float* __restrict__ h,
    const int* __restrict__ src_all,
    const int* __restrict__ offs,
    const int* __restrict__ edges,
    const _Float16* __restrict__ fw_upd_img, const float* __restrict__ fw_upd_b,
    const _Float16* __restrict__ fw_pre_img, const float* __restrict__ fw_pre_b,
    const _Float16* __restrict__ bw_upd_img, const float* __restrict__ bw_upd_b,
    const _Float16* __restrict__ bw_pre_img, const float* __restrict__ bw_pre_b,
    const float* __restrict__ mf_in, float* __restrict__ mf_out,
    const float* __restrict__ mb_in, float* __restrict__ mb_out,
    float* __restrict__ out, int step) {
  __shared__ __align__(16) _Float16 asplit[8192];   // 16 KB: hi [0..4095], lo [4096..]
  __shared__ __align__(16) float dbuf[4096];        // 16 KB D-scratch
  _Float16* ah = asplit;
  _Float16* al = asplit + 4096;
  int tid = threadIdx.x;
  int lane = tid & 63, wv = tid >> 6;               // wv = col-tile 0..7
  int c4 = tid & 31, rg2 = (tid >> 5) * 2;          // rows 0..30, 2 per thread
  bool is_fwd = blockIdx.x < 256;
  int tile = (blockIdx.x & 255) * 32;
  int level = is_fwd ? step : 15 - step;
  const _Float16* upd_img = is_fwd ? fw_upd_img : bw_upd_img;
  const float* upd_b = is_fwd ? fw_upd_b : bw_upd_b;
  const _Float16* pre_img = is_fwd ? fw_pre_img : bw_pre_img;
  const float* pre_b = is_fwd ? fw_pre_b : bw_pre_b;
  const float* m_in  = is_fwd ? mf_in : mb_in;
  float* m_out       = is_fwd ? mf_out : mb_out;
  bool has_gather = (step > 0);
  bool has_mout   = (step < 15);
  int col_off = is_fwd ? 0 : 128;

  // B-fragments for the update GEMM (32 VGPRs): latency overlaps the gather.
  h8 Bh[4], Bl[4];
  load_bfrags1(upd_img, wv, lane, Bh, Bl);

  // ---- phase A: gather z, write f16 splits into A-region ----
  if (has_gather) {
    if (is_fwd) {
      const int* src = src_all + (step - 1) * NE;
#pragma unroll
      for (int i = 0; i < 2; i++) {
        int r = rg2 + i;
        int p = tile + r;
        float4 v[8];
#pragma unroll
        for (int k = 0; k < 8; k++) {
          int s = src[p * 8 + k];
          v[k] = ld4(m_in + (size_t)s * 128 + c4 * 4);
        }
        float4 a;
        a.x = ((v[0].x + v[1].x) + (v[2].x + v[3].x)) + ((v[4].x + v[5].x) + (v[6].x + v[7].x));
        a.y = ((v[0].y + v[1].y) + (v[2].y + v[3].y)) + ((v[4].y + v[5].y) + (v[6].y + v[7].y));
        a.z = ((v[0].z + v[1].z) + (v[2].z + v[3].z)) + ((v[4].z + v[5].z) + (v[6].z + v[7].z));
        a.w = ((v[0].w + v[1].w) + (v[2].w + v[3].w)) + ((v[4].w + v[5].w) + (v[6].w + v[7].w));
        a.x *= 0.125f; a.y *= 0.125f; a.z *= 0.125f; a.w *= 0.125f;
        split_store(ah, al, r, c4 * 4, a);
      }
    } else {
      const int* off_l = offs + level * (PP + 1);
      const int* ep = edges + level * NE;
#pragma unroll
      for (int i = 0; i < 2; i++) {
        int r = rg2 + i;
        int q = tile + r;
        int e0 = off_l[q], e1 = off_l[q + 1];
        float4 a = {0.f, 0.f, 0.f, 0.f};
        int idx = e0;
        for (; idx + 4 <= e1; idx += 4) {
          int p0 = ep[idx], p1 = ep[idx + 1], p2 = ep[idx + 2], p3 = ep[idx + 3];
          float4 v0 = ld4(m_in + (size_t)p0 * 128 + c4 * 4);
          float4 v1 = ld4(m_in + (size_t)p1 * 128 + c4 * 4);
          float4 v2 = ld4(m_in + (size_t)p2 * 128 + c4 * 4);
          float4 v3 = ld4(m_in + (size_t)p3 * 128 + c4 * 4);
          a.x += (v0.x + v1.x) + (v2.x + v3.x);
          a.y += (v0.y + v1.y) + (v2.y + v3.y);
          a.z += (v0.z + v1.z) + (v2.z + v3.z);
          a.w += (v0.w + v1.w) + (v2.w + v3.w);
        }
        for (; idx < e1; idx++) {
          int p = ep[idx];
          float4 v = ld4(m_in + (size_t)p * 128 + c4 * 4);
          a.x += v.x; a.y += v.y; a.z += v.z; a.w += v.w;
        }
        float inv = (e1 > e0) ? 1.0f / (float)(e1 - e0) : 0.f;
        a.x *= inv; a.y *= inv; a.z *= inv; a.w *= inv;
        split_store(ah, al, r, c4 * 4, a);
      }
    }
  } else {
    float4 z = {0.f, 0.f, 0.f, 0.f};
#pragma unroll
    for (int i = 0; i < 2; i++) split_store(ah, al, rg2 + i, c4 * 4, z);
  }
  __syncthreads();                                  // bar1: A ready

  // ---- phase B: relu(z@upd_w + upd_b) via MFMA (B in registers) ----
  f4v acc[2];
#pragma unroll
  for (int rt = 0; rt < 2; rt++) acc[rt] = gemm_rt(ah, al, Bh, Bl, rt * 16, lane);
  {
    int r16 = lane & 15, kb = lane >> 4;
    int col = wv * 16 + r16;
    float b = upd_b[col];
#pragma unroll
    for (int rt = 0; rt < 2; rt++)
#pragma unroll
      for (int r = 0; r < 4; r++)
        dbuf[uswz(rt * 16 + kb * 4 + r, col)] = fmaxf(acc[rt][r] + b, 0.f);
  }
  if (has_mout) load_bfrags1(pre_img, wv, lane, Bh, Bl);   // latency hides under bar2+epilogue
  __syncthreads();                                  // bar2: D ready, A-reads done

  // ---- residual add + output write (coalesced) ----
  float4 u[2];
#pragma unroll
  for (int i = 0; i < 2; i++) {
    int r = rg2 + i;
    int n = level * PP + tile + r;
    float4 uv = *(const float4*)(dbuf + uswz(r, c4 * 4));
    float4 res = ld4(h + (size_t)n * 128 + c4 * 4);
    u[i].x = uv.x + res.x;
    u[i].y = uv.y + res.y;
    u[i].z = uv.z + res.z;
    u[i].w = uv.w + res.w;
    st4(out + (size_t)n * 256 + col_off + c4 * 4, u[i]);
  }

  // ---- phase C: m_out = relu(u @ pre_w + pre_b) ----
  if (has_mout) {
#pragma unroll
    for (int i = 0; i < 2; i++) split_store(ah, al, rg2 + i, c4 * 4, u[i]);  // safe after bar2
    __syncthreads();                                // bar3: new A ready, dbuf reads done
#pragma unroll
    for (int rt = 0; rt < 2; rt++) acc[rt] = gemm_rt(ah, al, Bh, Bl, rt * 16, lane);
    {
      int r16 = lane & 15, kb = lane >> 4;
      int col = wv * 16 + r16;
      float b = pre_b[col];
#pragma unroll
      for (int rt = 0; rt < 2; rt++)
#pragma unroll
        for (int r = 0; r < 4; r++)
          dbuf[uswz(rt * 16 + kb * 4 + r, col)] = fmaxf(acc[rt][r] + b, 0.f);
    }
    __syncthreads();                                // bar4: D ready
#pragma unroll
    for (int i = 0; i < 2; i++) {
      int r = rg2 + i;
      float4 m = *(const float4*)(dbuf + uswz(r, c4 * 4));
      st4(m_out + (size_t)(tile + r) * 128 + c4 * 4, m);
    }
  }
}

extern "C" void kernel_launch(void* const* d_in, const int* in_sizes, int n_in,
                              void* d_out, int out_size, void* d_ws, size_t ws_size,
                              hipStream_t stream) {
  const float* x      = (const float*)d_in[0];
  const int*   src    = (const int*)d_in[1];
  const float* nt_w1  = (const float*)d_in[2];
  const float* nt_b1  = (const float*)d_in[3];
  const float* nt_w2  = (const float*)d_in[4];
  const float* nt_b2  = (const float*)d_in[5];
  const float* f_pre_w = (const float*)d_in[6];
  const float* f_pre_b = (const float*)d_in[7];
  const float* f_upd_w = (const float*)d_in[8];
  const float* f_upd_b = (const float*)d_in[9];
  const float* b_pre_w = (const float*)d_in[10];
  const float* b_pre_b = (const float*)d_in[11];
  const float* b_upd_w = (const float*)d_in[12];
  const float* b_upd_b = (const float*)d_in[13];
  float* out = (float*)d_out;

  float* wsf = (float*)d_ws;
  float* h   = wsf;                                  // NN*DD
  float* mf0 = h + (size_t)NN * DD;                  // PP*DD each
  float* mf1 = mf0 + (size_t)PP * DD;
  float* mb0 = mf1 + (size_t)PP * DD;
  float* mb1 = mb0 + (size_t)PP * DD;
  int* deg    = (int*)(mb1 + (size_t)PP * DD);       // NLVL*PP
  int* offs   = deg + NLVL * PP;                     // NLVL*(PP+1)
  int* cursor = offs + NLVL * (PP + 1);              // NLVL*PP
  int* edges  = cursor + NLVL * PP;                  // NLVL*NE

  // fragment-ordered f16 hi/lo weight images (32768 halves = 64KB each)
  uintptr_t ip = (uintptr_t)(edges + (size_t)NLVL * NE);
  ip = (ip + 15) & ~(uintptr_t)15;
  _Float16* img = (_Float16*)ip;
  _Float16* i_ntw1 = img;                 // mat 0
  _Float16* i_ntw2 = img + 32768;         // mat 1
  _Float16* i_fupd = img + 2 * 32768;     // mat 2
  _Float16* i_fpre = img + 3 * 32768;     // mat 3
  _Float16* i_bupd = img + 4 * 32768;     // mat 4
  _Float16* i_bpre = img + 5 * 32768;     // mat 5

  hipMemsetAsync(deg, 0, (size_t)NLVL * PP * sizeof(int), stream);
  prep_all<<<48, 256, 0, stream>>>(nt_w1, nt_w2, f_upd_w, f_pre_w, b_upd_w, b_pre_w, img);

  nt_kernel<<<NN / 64, 512, 0, stream>>>(x, i_ntw1, nt_b1, i_ntw2, nt_b2, h);
  csr_count<<<NLVL * NE / 256, 256, 0, stream>>>(src, deg);
  csr_scan<<<NLVL, 256, 0, stream>>>(deg, offs, cursor);
  csr_fill<<<NLVL * NE / 256, 256, 0, stream>>>(src, cursor, edges);

  for (int s = 0; s < 16; s++) {
    const float* mf_in = (s & 1) ? mf0 : mf1;
    float* mf_out      = (s & 1) ? mf1 : mf0;
    const float* mb_in = (s & 1) ? mb0 : mb1;
    float* mb_out      = (s & 1) ? mb1 : mb0;
    mp_step<<<512, 512, 0, stream>>>(h, src, offs, edges,
                                     i_fupd, f_upd_b, i_fpre, f_pre_b,
                                     i_bupd, b_upd_b, i_bpre, b_pre_b,
                                     mf_in, mf_out, mb_in, mb_out, out, s);
  }
}